// Round 1
// baseline (3153.344 us; speedup 1.0000x reference)
//
#include <hip/hip_runtime.h>
#include <hip/hip_bf16.h>
#include <math.h>

#define B_  16
#define S_  626
#define H_  768
#define NH_ 12
#define DH_ 64
#define BH_ (B_*NH_)          // 192
#define M_  (B_*S_)           // 10016
#define SM1 (S_-1)            // 625

// ---------------------------------------------------------------------------
// Generic C = A(MxK) @ W(KxN) + bias(N), fp32, 64x64 tile, 4x4 per thread.
// MODE 0: C row-major (M x N).
// MODE 1: head-scatter epilogue: row=(b,s), col=(h,d) -> out[((b*NH+h)*S+s)*DH+d]
// ---------------------------------------------------------------------------
template<int MODE>
__global__ void gemm_bias(const float* __restrict__ A, const float* __restrict__ W,
                          const float* __restrict__ bias, float* __restrict__ out,
                          int M, int N, int K) {
    __shared__ float As[16][64];
    __shared__ float Bs[16][64];
    const int tid = threadIdx.x;
    const int tx = tid & 15, ty = tid >> 4;
    const int rowBase = blockIdx.y * 64;
    const int colBase = blockIdx.x * 64;
    float c[4][4] = {};

    for (int k0 = 0; k0 < K; k0 += 16) {
        #pragma unroll
        for (int l = 0; l < 4; ++l) {
            int idx = tid + l * 256;
            int kk = idx & 15, m = idx >> 4;
            int row = rowBase + m;
            As[kk][m] = (row < M) ? A[(size_t)row * K + k0 + kk] : 0.f;
        }
        #pragma unroll
        for (int l = 0; l < 4; ++l) {
            int idx = tid + l * 256;
            int n = idx & 63, kk = idx >> 6;
            int col = colBase + n;
            Bs[kk][n] = (col < N) ? W[(size_t)(k0 + kk) * N + col] : 0.f;
        }
        __syncthreads();
        #pragma unroll
        for (int kk = 0; kk < 16; ++kk) {
            float a[4], b[4];
            #pragma unroll
            for (int i = 0; i < 4; ++i) a[i] = As[kk][ty * 4 + i];
            #pragma unroll
            for (int j = 0; j < 4; ++j) b[j] = Bs[kk][tx * 4 + j];
            #pragma unroll
            for (int i = 0; i < 4; ++i)
                #pragma unroll
                for (int j = 0; j < 4; ++j) c[i][j] += a[i] * b[j];
        }
        __syncthreads();
    }

    #pragma unroll
    for (int i = 0; i < 4; ++i) {
        int row = rowBase + ty * 4 + i;
        if (row >= M) continue;
        #pragma unroll
        for (int j = 0; j < 4; ++j) {
            int col = colBase + tx * 4 + j;
            if (col >= N) continue;
            float val = c[i][j] + bias[col];
            if (MODE == 0) {
                out[(size_t)row * N + col] = val;
            } else {
                int b_ = row / S_, s_ = row - b_ * S_;
                int h_ = col >> 6, d_ = col & 63;   // DH=64
                out[(((size_t)(b_ * NH_ + h_) * S_ + s_) << 6) + d_] = val;
            }
        }
    }
}

// ---------------------------------------------------------------------------
// scores[bh, q, k] = (Q[bh,q,:] . K[bh,k,:]) * 0.125   (DH=64)
// 32x32 output tile per block, 256 threads, 2x2 per thread.
// ---------------------------------------------------------------------------
__global__ void scores_kernel(const float* __restrict__ q, const float* __restrict__ k,
                              float* __restrict__ scores) {
    const int bh = blockIdx.z;
    const int qbase = blockIdx.y * 32;
    const int kbase = blockIdx.x * 32;
    __shared__ float Qs[32][64];
    __shared__ float Ks[32][64];
    const int tid = threadIdx.x;
    const float* qb = q + (size_t)bh * S_ * DH_;
    const float* kb = k + (size_t)bh * S_ * DH_;
    #pragma unroll
    for (int l = 0; l < 8; ++l) {
        int idx = tid + l * 256;
        int d = idx & 63, r = idx >> 6;
        Qs[r][d] = (qbase + r < S_) ? qb[((size_t)(qbase + r) << 6) + d] : 0.f;
        Ks[r][d] = (kbase + r < S_) ? kb[((size_t)(kbase + r) << 6) + d] : 0.f;
    }
    __syncthreads();
    const int tx = tid & 15, ty = tid >> 4;
    float acc[2][2] = {};
    #pragma unroll 8
    for (int d = 0; d < 64; ++d) {
        float a0 = Qs[ty * 2][d],     a1 = Qs[ty * 2 + 1][d];
        float b0 = Ks[tx * 2][d],     b1 = Ks[tx * 2 + 1][d];
        acc[0][0] += a0 * b0; acc[0][1] += a0 * b1;
        acc[1][0] += a1 * b0; acc[1][1] += a1 * b1;
    }
    #pragma unroll
    for (int i = 0; i < 2; ++i) {
        int qi = qbase + ty * 2 + i;
        if (qi >= S_) continue;
        #pragma unroll
        for (int j = 0; j < 2; ++j) {
            int ki = kbase + tx * 2 + j;
            if (ki >= S_) continue;
            scores[((size_t)bh * S_ + qi) * S_ + ki] = acc[i][j] * 0.125f;
        }
    }
}

// ---------------------------------------------------------------------------
// Row-0 special case: max over row0, then +max*0.25 where mask_full < 0.5.
// One block per (b,h).
// ---------------------------------------------------------------------------
__global__ void row0_kernel(float* __restrict__ scores, const float* __restrict__ mask) {
    const int bh = blockIdx.x;
    const int b = bh / NH_;
    float* row = scores + (size_t)bh * S_ * S_;   // row 0
    __shared__ float red[256];
    const int tid = threadIdx.x;
    float m = -INFINITY;
    for (int k = tid; k < S_; k += 256) m = fmaxf(m, row[k]);
    red[tid] = m;
    __syncthreads();
    for (int s = 128; s > 0; s >>= 1) {
        if (tid < s) red[tid] = fmaxf(red[tid], red[tid + s]);
        __syncthreads();
    }
    const float mx = red[0];
    for (int k = tid; k < S_; k += 256) {
        float mf = (k == 0) ? 0.f : mask[(size_t)b * SM1 + k - 1];
        if (mf < 0.5f) row[k] += mx * 0.25f;
    }
}

// ---------------------------------------------------------------------------
// In-place softmax over the last axis; one wave (64 lanes) per row.
// Lane 0 snapshots the original k=0 element into col0 (for sm2).
// ---------------------------------------------------------------------------
__global__ void softmax_rows(float* __restrict__ scores, float* __restrict__ col0) {
    const int row = blockIdx.x * 4 + (threadIdx.x >> 6);
    const int lane = threadIdx.x & 63;
    if (row >= BH_ * S_) return;
    float* r = scores + (size_t)row * S_;
    float vals[10];
    float mx = -INFINITY;
    #pragma unroll
    for (int i = 0; i < 10; ++i) {
        int k = lane + i * 64;
        vals[i] = (k < S_) ? r[k] : -INFINITY;
        mx = fmaxf(mx, vals[i]);
    }
    #pragma unroll
    for (int off = 32; off > 0; off >>= 1) mx = fmaxf(mx, __shfl_xor(mx, off, 64));
    float ex[10];
    float sum = 0.f;
    #pragma unroll
    for (int i = 0; i < 10; ++i) {
        ex[i] = (lane + i * 64 < S_) ? expf(vals[i] - mx) : 0.f;
        sum += ex[i];
    }
    #pragma unroll
    for (int off = 32; off > 0; off >>= 1) sum += __shfl_xor(sum, off, 64);
    const float inv = 1.f / sum;
    if (lane == 0) col0[row] = vals[0];
    #pragma unroll
    for (int i = 0; i < 10; ++i) {
        int k = lane + i * 64;
        if (k < S_) r[k] = ex[i] * inv;
    }
}

// ---------------------------------------------------------------------------
// sm2[bh, q] = softmax over q of col0[bh, :]. One block per (b,h).
// ---------------------------------------------------------------------------
__global__ void sm2_kernel(const float* __restrict__ col0, float* __restrict__ out) {
    const int bh = blockIdx.x;
    const float* c = col0 + (size_t)bh * S_;
    __shared__ float red[256];
    const int tid = threadIdx.x;
    float m = -INFINITY;
    for (int q = tid; q < S_; q += 256) m = fmaxf(m, c[q]);
    red[tid] = m;
    __syncthreads();
    for (int s = 128; s > 0; s >>= 1) {
        if (tid < s) red[tid] = fmaxf(red[tid], red[tid + s]);
        __syncthreads();
    }
    const float mx = red[0];
    __syncthreads();
    float sum = 0.f;
    for (int q = tid; q < S_; q += 256) sum += expf(c[q] - mx);
    red[tid] = sum;
    __syncthreads();
    for (int s = 128; s > 0; s >>= 1) {
        if (tid < s) red[tid] += red[tid + s];
        __syncthreads();
    }
    const float inv = 1.f / red[0];
    for (int q = tid; q < S_; q += 256) out[(size_t)bh * S_ + q] = expf(c[q] - mx) * inv;
}

// ---------------------------------------------------------------------------
// ctx[b, q, h*64+d] = sum_k probs[bh,q,k] * V[bh,k,d].
// 32 rows x 64 cols per block, 256 threads, 8 rows per thread.
// ---------------------------------------------------------------------------
__global__ void ctx_kernel(const float* __restrict__ probs, const float* __restrict__ v,
                           float* __restrict__ ctx) {
    const int bh = blockIdx.y;
    const int qbase = blockIdx.x * 32;
    const int b = bh / NH_, h = bh - b * NH_;
    __shared__ float Ps[32][33];
    __shared__ float Vs[32][64];
    const int tid = threadIdx.x;
    const int col = tid & 63;
    const int rgrp = tid >> 6;
    float acc[8] = {};
    const float* pb = probs + (size_t)bh * S_ * S_;
    const float* vb = v + (size_t)bh * S_ * DH_;
    for (int k0 = 0; k0 < S_; k0 += 32) {
        #pragma unroll
        for (int l = 0; l < 4; ++l) {
            int idx = tid + l * 256;
            int kk = idx & 31, r = idx >> 5;
            int qq = qbase + r, kk2 = k0 + kk;
            Ps[r][kk] = (qq < S_ && kk2 < S_) ? pb[(size_t)qq * S_ + kk2] : 0.f;
        }
        #pragma unroll
        for (int l = 0; l < 8; ++l) {
            int idx = tid + l * 256;
            int d = idx & 63, r = idx >> 6;
            int kk2 = k0 + r;
            Vs[r][d] = (kk2 < S_) ? vb[((size_t)kk2 << 6) + d] : 0.f;
        }
        __syncthreads();
        #pragma unroll
        for (int kk = 0; kk < 32; ++kk) {
            float vv = Vs[kk][col];
            #pragma unroll
            for (int i = 0; i < 8; ++i) acc[i] += Ps[rgrp * 8 + i][kk] * vv;
        }
        __syncthreads();
    }
    #pragma unroll
    for (int i = 0; i < 8; ++i) {
        int qq = qbase + rgrp * 8 + i;
        if (qq < S_) ctx[((size_t)(b * S_ + qq)) * H_ + h * DH_ + col] = acc[i];
    }
}

// ---------------------------------------------------------------------------
extern "C" void kernel_launch(void* const* d_in, const int* in_sizes, int n_in,
                              void* d_out, int out_size, void* d_ws, size_t ws_size,
                              hipStream_t stream) {
    const float* hs   = (const float*)d_in[0];
    const float* mask = (const float*)d_in[1];
    const float* Wq   = (const float*)d_in[2];
    const float* bq   = (const float*)d_in[3];
    const float* Wk   = (const float*)d_in[4];
    const float* bk   = (const float*)d_in[5];
    const float* Wv   = (const float*)d_in[6];
    const float* bv   = (const float*)d_in[7];
    const float* Wo   = (const float*)d_in[8];
    const float* bo   = (const float*)d_in[9];

    float* out     = (float*)d_out;                              // (B,S,H)
    float* weights = out + (size_t)B_ * S_ * H_;                 // (B,NH,S,S)
    float* sm2     = weights + (size_t)BH_ * S_ * S_;            // (B,NH,S)

    float* ws    = (float*)d_ws;
    const size_t headSz = (size_t)BH_ * S_ * DH_;                // 7,692,288
    float* q_ws  = ws;
    float* k_ws  = q_ws + headSz;
    float* v_ws  = k_ws + headSz;
    float* col0  = v_ws + headSz;                                // BH*S floats
    float* ctx_ws = q_ws;                                        // Q dead after scores

    dim3 gemmGrid(12, 157);     // N=768/64, ceil(10016/64)
    gemm_bias<1><<<gemmGrid, 256, 0, stream>>>(hs, Wq, bq, q_ws, M_, H_, H_);
    gemm_bias<1><<<gemmGrid, 256, 0, stream>>>(hs, Wk, bk, k_ws, M_, H_, H_);
    gemm_bias<1><<<gemmGrid, 256, 0, stream>>>(hs, Wv, bv, v_ws, M_, H_, H_);

    scores_kernel<<<dim3(20, 20, BH_), 256, 0, stream>>>(q_ws, k_ws, weights);
    row0_kernel<<<BH_, 256, 0, stream>>>(weights, mask);
    softmax_rows<<<(BH_ * S_) / 4, 256, 0, stream>>>(weights, col0);
    sm2_kernel<<<BH_, 256, 0, stream>>>(col0, sm2);
    ctx_kernel<<<dim3(20, BH_), 256, 0, stream>>>(weights, v_ws, ctx_ws);

    gemm_bias<0><<<gemmGrid, 256, 0, stream>>>(ctx_ws, Wo, bo, out, M_, H_, H_);
}

// Round 2
// 2049.900 us; speedup vs baseline: 1.5383x; 1.5383x over previous
//
#include <hip/hip_runtime.h>
#include <hip/hip_bf16.h>
#include <math.h>

#define B_  16
#define S_  626
#define H_  768
#define NH_ 12
#define DH_ 64
#define BH_ (B_*NH_)          // 192
#define M_  (B_*S_)           // 10016
#define SM1 (S_-1)            // 625

// ---------------------------------------------------------------------------
// Generic C = A(MxK) @ W(KxN) + bias(N), fp32, 64x64 tile, 4x4 per thread,
// K-chunk 32, A-tile padded to stride 68 (conflict-free staging + aligned b128).
// MODE 0: C row-major (M x N).
// MODE 1: head-scatter epilogue: row=(b,s), col=(h,d) -> out[((b*NH+h)*S+s)*DH+d]
// ---------------------------------------------------------------------------
template<int MODE>
__global__ void gemm_bias(const float* __restrict__ A, const float* __restrict__ W,
                          const float* __restrict__ bias, float* __restrict__ out,
                          int M, int N, int K) {
    __shared__ float As[32][68];   // [k][m]  (transposed A tile)
    __shared__ float Bs[32][64];   // [k][n]
    const int tid = threadIdx.x;
    const int tx = tid & 15, ty = tid >> 4;
    const int rowBase = blockIdx.y * 64;
    const int colBase = blockIdx.x * 64;
    float c[4][4] = {};

    for (int k0 = 0; k0 < K; k0 += 32) {
        // A tile: 64 rows x 32 k -> As[k][m]; consecutive lanes read consecutive k
        #pragma unroll
        for (int l = 0; l < 8; ++l) {
            int idx = tid + l * 256;
            int kk = idx & 31, m = idx >> 5;
            int row = rowBase + m;
            As[kk][m] = (row < M) ? A[(size_t)row * K + k0 + kk] : 0.f;
        }
        // B tile: 32 k x 64 n
        #pragma unroll
        for (int l = 0; l < 8; ++l) {
            int idx = tid + l * 256;
            int n = idx & 63, kk = idx >> 6;
            Bs[kk][n] = W[(size_t)(k0 + kk) * N + colBase + n];
        }
        __syncthreads();
        #pragma unroll
        for (int kk = 0; kk < 32; ++kk) {
            float a[4], b[4];
            *(float4*)a = *(const float4*)&As[kk][ty * 4];
            *(float4*)b = *(const float4*)&Bs[kk][tx * 4];
            #pragma unroll
            for (int i = 0; i < 4; ++i)
                #pragma unroll
                for (int j = 0; j < 4; ++j) c[i][j] += a[i] * b[j];
        }
        __syncthreads();
    }

    #pragma unroll
    for (int i = 0; i < 4; ++i) {
        int row = rowBase + ty * 4 + i;
        if (row >= M) continue;
        int col = colBase + tx * 4;
        float4 val;
        val.x = c[i][0] + bias[col + 0];
        val.y = c[i][1] + bias[col + 1];
        val.z = c[i][2] + bias[col + 2];
        val.w = c[i][3] + bias[col + 3];
        if (MODE == 0) {
            *(float4*)&out[(size_t)row * N + col] = val;
        } else {
            int b_ = row / S_, s_ = row - b_ * S_;
            int h_ = col >> 6, d_ = col & 63;   // DH=64, tx*4 stays within one head
            *(float4*)&out[(((size_t)(b_ * NH_ + h_) * S_ + s_) << 6) + d_] = val;
        }
    }
}

// ---------------------------------------------------------------------------
// scores[bh, q, k] = (Q[bh,q,:] . K[bh,k,:]) * 0.125   (DH=64)
// 64x64 output tile, full K=64 staged transposed [d][row], stride 68.
// 4x4 per thread, float4 LDS reads -> 16 FMA per 2 ds_read_b128.
// ---------------------------------------------------------------------------
__global__ void scores_kernel(const float* __restrict__ q, const float* __restrict__ k,
                              float* __restrict__ scores) {
    const int bh = blockIdx.z;
    const int qbase = blockIdx.y * 64;
    const int kbase = blockIdx.x * 64;
    __shared__ float Qs[64][68];   // [d][qrow]
    __shared__ float Ks[64][68];   // [d][krow]
    const int tid = threadIdx.x;
    const float* qb = q + (size_t)bh * S_ * DH_;
    const float* kb = k + (size_t)bh * S_ * DH_;
    #pragma unroll
    for (int l = 0; l < 16; ++l) {
        int idx = tid + l * 256;
        int d = idx & 63, r = idx >> 6;       // consecutive lanes: consecutive d (coalesced)
        Qs[d][r] = (qbase + r < S_) ? qb[((size_t)(qbase + r) << 6) + d] : 0.f;
        Ks[d][r] = (kbase + r < S_) ? kb[((size_t)(kbase + r) << 6) + d] : 0.f;
    }
    __syncthreads();
    const int tx = tid & 15, ty = tid >> 4;
    float c[4][4] = {};
    #pragma unroll 4
    for (int d = 0; d < 64; ++d) {
        float a[4], b[4];
        *(float4*)a = *(const float4*)&Qs[d][ty * 4];
        *(float4*)b = *(const float4*)&Ks[d][tx * 4];
        #pragma unroll
        for (int i = 0; i < 4; ++i)
            #pragma unroll
            for (int j = 0; j < 4; ++j) c[i][j] += a[i] * b[j];
    }
    #pragma unroll
    for (int i = 0; i < 4; ++i) {
        int qi = qbase + ty * 4 + i;
        if (qi >= S_) continue;
        float* row = scores + ((size_t)bh * S_ + qi) * S_;
        #pragma unroll
        for (int j = 0; j < 4; ++j) {
            int ki = kbase + tx * 4 + j;
            if (ki < S_) row[ki] = c[i][j] * 0.125f;
        }
    }
}

// ---------------------------------------------------------------------------
// Row-0 special case: max over row0, then +max*0.25 where mask_full < 0.5.
// ---------------------------------------------------------------------------
__global__ void row0_kernel(float* __restrict__ scores, const float* __restrict__ mask) {
    const int bh = blockIdx.x;
    const int b = bh / NH_;
    float* row = scores + (size_t)bh * S_ * S_;   // row 0
    __shared__ float red[256];
    const int tid = threadIdx.x;
    float m = -INFINITY;
    for (int k = tid; k < S_; k += 256) m = fmaxf(m, row[k]);
    red[tid] = m;
    __syncthreads();
    for (int s = 128; s > 0; s >>= 1) {
        if (tid < s) red[tid] = fmaxf(red[tid], red[tid + s]);
        __syncthreads();
    }
    const float mx = red[0];
    for (int k = tid; k < S_; k += 256) {
        float mf = (k == 0) ? 0.f : mask[(size_t)b * SM1 + k - 1];
        if (mf < 0.5f) row[k] += mx * 0.25f;
    }
}

// ---------------------------------------------------------------------------
// In-place softmax over last axis; one wave per row; snapshots col 0 for sm2.
// ---------------------------------------------------------------------------
__global__ void softmax_rows(float* __restrict__ scores, float* __restrict__ col0) {
    const int row = blockIdx.x * 4 + (threadIdx.x >> 6);
    const int lane = threadIdx.x & 63;
    if (row >= BH_ * S_) return;
    float* r = scores + (size_t)row * S_;
    float vals[10];
    float mx = -INFINITY;
    #pragma unroll
    for (int i = 0; i < 10; ++i) {
        int k = lane + i * 64;
        vals[i] = (k < S_) ? r[k] : -INFINITY;
        mx = fmaxf(mx, vals[i]);
    }
    #pragma unroll
    for (int off = 32; off > 0; off >>= 1) mx = fmaxf(mx, __shfl_xor(mx, off, 64));
    float ex[10];
    float sum = 0.f;
    #pragma unroll
    for (int i = 0; i < 10; ++i) {
        ex[i] = (lane + i * 64 < S_) ? expf(vals[i] - mx) : 0.f;
        sum += ex[i];
    }
    #pragma unroll
    for (int off = 32; off > 0; off >>= 1) sum += __shfl_xor(sum, off, 64);
    const float inv = 1.f / sum;
    if (lane == 0) col0[row] = vals[0];
    #pragma unroll
    for (int i = 0; i < 10; ++i) {
        int k = lane + i * 64;
        if (k < S_) r[k] = ex[i] * inv;
    }
}

// ---------------------------------------------------------------------------
// sm2[bh, q] = softmax over q of col0[bh, :].
// ---------------------------------------------------------------------------
__global__ void sm2_kernel(const float* __restrict__ col0, float* __restrict__ out) {
    const int bh = blockIdx.x;
    const float* c = col0 + (size_t)bh * S_;
    __shared__ float red[256];
    const int tid = threadIdx.x;
    float m = -INFINITY;
    for (int q = tid; q < S_; q += 256) m = fmaxf(m, c[q]);
    red[tid] = m;
    __syncthreads();
    for (int s = 128; s > 0; s >>= 1) {
        if (tid < s) red[tid] = fmaxf(red[tid], red[tid + s]);
        __syncthreads();
    }
    const float mx = red[0];
    __syncthreads();
    float sum = 0.f;
    for (int q = tid; q < S_; q += 256) sum += expf(c[q] - mx);
    red[tid] = sum;
    __syncthreads();
    for (int s = 128; s > 0; s >>= 1) {
        if (tid < s) red[tid] += red[tid + s];
        __syncthreads();
    }
    const float inv = 1.f / red[0];
    for (int q = tid; q < S_; q += 256) out[(size_t)bh * S_ + q] = expf(c[q] - mx) * inv;
}

// ---------------------------------------------------------------------------
// ctx[b, q, h*64+d] = sum_k probs[bh,q,k] * V[bh,k,d]
// 64x64 tile (full DH), K chunked by 32, 4x4/thread, float4 LDS reads.
// ---------------------------------------------------------------------------
__global__ void ctx_kernel(const float* __restrict__ probs, const float* __restrict__ v,
                           float* __restrict__ ctx) {
    const int bh = blockIdx.y;
    const int qbase = blockIdx.x * 64;
    const int b = bh / NH_, h = bh - b * NH_;
    __shared__ float Ps[32][68];   // [k][q]
    __shared__ float Vs[32][64];   // [k][d]
    const int tid = threadIdx.x;
    const int tx = tid & 15, ty = tid >> 4;
    float c[4][4] = {};
    const float* pb = probs + (size_t)bh * S_ * S_;
    const float* vb = v + (size_t)bh * S_ * DH_;
    for (int k0 = 0; k0 < S_; k0 += 32) {
        #pragma unroll
        for (int l = 0; l < 8; ++l) {
            int idx = tid + l * 256;
            int kk = idx & 31, r = idx >> 5;
            int qq = qbase + r, k2 = k0 + kk;
            Ps[kk][r] = (qq < S_ && k2 < S_) ? pb[(size_t)qq * S_ + k2] : 0.f;
        }
        #pragma unroll
        for (int l = 0; l < 8; ++l) {
            int idx = tid + l * 256;
            int d = idx & 63, r = idx >> 6;
            int k2 = k0 + r;
            Vs[r][d] = (k2 < S_) ? vb[((size_t)k2 << 6) + d] : 0.f;
        }
        __syncthreads();
        #pragma unroll
        for (int kk = 0; kk < 32; ++kk) {
            float a[4], b[4];
            *(float4*)a = *(const float4*)&Ps[kk][ty * 4];
            *(float4*)b = *(const float4*)&Vs[kk][tx * 4];
            #pragma unroll
            for (int i = 0; i < 4; ++i)
                #pragma unroll
                for (int j = 0; j < 4; ++j) c[i][j] += a[i] * b[j];
        }
        __syncthreads();
    }
    #pragma unroll
    for (int i = 0; i < 4; ++i) {
        int qq = qbase + ty * 4 + i;
        if (qq >= S_) continue;
        int d = tx * 4;
        *(float4*)&ctx[((size_t)(b * S_ + qq)) * H_ + h * DH_ + d] = *(float4*)c[i];
    }
}

// ---------------------------------------------------------------------------
extern "C" void kernel_launch(void* const* d_in, const int* in_sizes, int n_in,
                              void* d_out, int out_size, void* d_ws, size_t ws_size,
                              hipStream_t stream) {
    const float* hs   = (const float*)d_in[0];
    const float* mask = (const float*)d_in[1];
    const float* Wq   = (const float*)d_in[2];
    const float* bq   = (const float*)d_in[3];
    const float* Wk   = (const float*)d_in[4];
    const float* bk   = (const float*)d_in[5];
    const float* Wv   = (const float*)d_in[6];
    const float* bv   = (const float*)d_in[7];
    const float* Wo   = (const float*)d_in[8];
    const float* bo   = (const float*)d_in[9];

    float* out     = (float*)d_out;                              // (B,S,H)
    float* weights = out + (size_t)B_ * S_ * H_;                 // (B,NH,S,S)
    float* sm2     = weights + (size_t)BH_ * S_ * S_;            // (B,NH,S)

    float* ws    = (float*)d_ws;
    const size_t headSz = (size_t)BH_ * S_ * DH_;                // 7,692,288
    float* q_ws  = ws;
    float* k_ws  = q_ws + headSz;
    float* v_ws  = k_ws + headSz;
    float* col0  = v_ws + headSz;                                // BH*S floats
    float* ctx_ws = q_ws;                                        // Q dead after scores

    dim3 gemmGrid(12, 157);     // N=768/64, ceil(10016/64)
    gemm_bias<1><<<gemmGrid, 256, 0, stream>>>(hs, Wq, bq, q_ws, M_, H_, H_);
    gemm_bias<1><<<gemmGrid, 256, 0, stream>>>(hs, Wk, bk, k_ws, M_, H_, H_);
    gemm_bias<1><<<gemmGrid, 256, 0, stream>>>(hs, Wv, bv, v_ws, M_, H_, H_);

    scores_kernel<<<dim3(10, 10, BH_), 256, 0, stream>>>(q_ws, k_ws, weights);
    row0_kernel<<<BH_, 256, 0, stream>>>(weights, mask);
    softmax_rows<<<(BH_ * S_) / 4, 256, 0, stream>>>(weights, col0);
    sm2_kernel<<<BH_, 256, 0, stream>>>(col0, sm2);
    ctx_kernel<<<dim3(10, BH_), 256, 0, stream>>>(weights, v_ws, ctx_ws);

    gemm_bias<0><<<gemmGrid, 256, 0, stream>>>(ctx_ws, Wo, bo, out, M_, H_, H_);
}